// Round 6
// baseline (575.589 us; speedup 1.0000x reference)
//
#include <hip/hip_runtime.h>
#include <hip/hip_bf16.h>

#define NS   32768
#define DD   256
#define NPOS 4
#define IDN  4096

#define NCHUNK 16
#define CHCOLS (NS / NCHUNK)     // 2048
#define STEPS  (CHCOLS / 128)    // 16 (128 cols per block-step)

typedef __attribute__((ext_vector_type(8))) short short8;
typedef __attribute__((ext_vector_type(4))) float f32x4;

__device__ __forceinline__ unsigned short f2bf(float f) {
    unsigned int u = __builtin_bit_cast(unsigned int, f);
    unsigned int r = (u + 0x7FFFu + ((u >> 16) & 1u)) >> 16;
    return (unsigned short)r;
}

__device__ __forceinline__ void gload16(const void* g, void* lds) {
    __builtin_amdgcn_global_load_lds(
        (const __attribute__((address_space(1))) unsigned int*)g,
        (__attribute__((address_space(3))) unsigned int*)lds, 16, 0, 0);
}

// ---------------- prep kernels ----------------

__global__ void build_idx_k(const int* __restrict__ targets, int* icnt, int* idx) {
    int i = blockIdx.x * 256 + threadIdx.x;
    if (i < NS) {
        int t = targets[i];
        int slot = atomicAdd(&icnt[t], 1);
        if (slot < 16) idx[t * 16 + slot] = i;
    }
}

__global__ void conv_k(const float* __restrict__ in, unsigned short* __restrict__ Xb,
                       float* __restrict__ x2) {
    int row  = blockIdx.x * 4 + (threadIdx.x >> 6);
    int lane = threadIdx.x & 63;
    const float4 v = *(const float4*)&in[(size_t)row * DD + lane * 4];
    ushort4 u;
    u.x = f2bf(v.x); u.y = f2bf(v.y); u.z = f2bf(v.z); u.w = f2bf(v.w);
    *(ushort4*)&Xb[(size_t)row * DD + lane * 4] = u;
    float sq = v.x * v.x + v.y * v.y + v.z * v.z + v.w * v.w;
    #pragma unroll
    for (int m = 1; m < 64; m <<= 1) sq += __shfl_xor(sq, m, 64);
    if (lane == 0) x2[row] = sq;
}

__global__ void centers_k(const float* __restrict__ in, const int* __restrict__ idx,
                          const int* __restrict__ icnt, const int* __restrict__ targets,
                          unsigned short* __restrict__ Cb, float* __restrict__ c2,
                          int* __restrict__ cid) {
    int c = blockIdx.x, d = threadIdx.x;
    int n = icnt[c]; if (n < 1) n = 1; if (n > 16) n = 16;
    float s = 0.f;
    for (int j = 0; j < n; ++j) s += in[(size_t)idx[c * 16 + j] * DD + d];
    float mean = s / (float)n;
    Cb[(size_t)c * DD + d] = f2bf(mean);
    float sq = mean * mean;
    #pragma unroll
    for (int m = 1; m < 64; m <<= 1) sq += __shfl_xor(sq, m, 64);
    __shared__ float sb[4];
    int lane = d & 63, w = d >> 6;
    if (lane == 0) sb[w] = sq;
    __syncthreads();
    if (d == 0) {
        c2[c] = sb[0] + sb[1] + sb[2] + sb[3];
        cid[c] = targets[c * NPOS];
    }
}

__global__ void dneg_k(const float* __restrict__ negsum,
                       const float* __restrict__ negcnt, float* dneg) {
    int c = blockIdx.x * 256 + threadIdx.x;
    if (c < IDN) {
        float d = negsum[c] / fmaxf(negcnt[c], 1.0f);
        dneg[c] = d * d;          // dn^2: pass-2 compares in d2 domain
    }
}

// ---------------- A-resident N-streaming MFMA pass ----------------
// 1024 blocks = 64 row-blocks x 16 chunks; 256 threads (4 waves, 2 row x 2 col).
// Wave tile 32x64; A panel 64x256 bf16 in LDS (32KB, staged once, one barrier).
// B from global (XCD L2/L3) with a DEPTH-4 register ring: at kk, consume slot
// kk&3, then reissue that slot for kk+4 (kk>=4 issues NEXT step's loads, which
// stay in flight across the whole epilogue) -> ~250-600cy latency coverage.

template <int PASS>
__global__ __launch_bounds__(256, 3)
void mpass_k(const unsigned short* __restrict__ Cb, const unsigned short* __restrict__ Xb,
             const float* __restrict__ c2, const float* __restrict__ x2,
             const int* __restrict__ targets, const int* __restrict__ cid,
             float* negsum, float* negcnt, const float* __restrict__ dneg,
             float* hardsum, float* hardcnt, float* scal) {
    __shared__ unsigned short As[32 * 512];   // [kstep*4+rowblock][lane*8] = 32KB
    __shared__ float red[8];

    const int tid = threadIdx.x;
    const int l  = tid & 63;
    const int w  = tid >> 6;      // wave 0..3
    const int wr = w >> 1;        // 0..1 : row half (32 rows)
    const int wc = w & 1;         // 0..1 : col half (64 cols)
    const int lr = l & 15;
    const int lc = l >> 4;
    const int bid = blockIdx.x;
    const int ch = bid & (NCHUNK - 1);
    const int bm = bid >> 4;      // row block 0..63

    // ---- stage A panel once: wave w stages ksteps {2w,2w+1}, rowblocks 0..3 ----
    {
        #pragma unroll
        for (int s2 = 0; s2 < 2; ++s2) {
            const int ks = w * 2 + s2;
            const unsigned short* src = Cb + (size_t)(bm * 64 + lr) * DD + ks * 32 + lc * 8;
            #pragma unroll
            for (int rb = 0; rb < 4; ++rb)
                gload16(src + (size_t)rb * 16 * DD, &As[(ks * 4 + rb) * 512]);
        }
    }

    const int colw0 = ch * CHCOLS + wc * 64;
    const unsigned short* bbase = Xb + (size_t)(colw0 + lr) * DD + lc * 8;

    // ---- depth-4 B ring: slot s holds kk === s (mod 4) ----
    short8 bR[4][4];
    #pragma unroll
    for (int s = 0; s < 4; ++s)
        #pragma unroll
        for (int nf = 0; nf < 4; ++nf)
            bR[s][nf] = *(const short8*)(bbase + (size_t)(nf * 16) * DD + s * 32);

    __syncthreads();   // A panel ready (drains vmcnt; B ring regs also landed)

    const int gr0 = bm * 64 + wr * 32;
    float c2v[8]; int cidv[8]; float dnv[8];
    #pragma unroll
    for (int mf = 0; mf < 2; ++mf)
        #pragma unroll
        for (int r = 0; r < 4; ++r) {
            int row = gr0 + mf * 16 + lc * 4 + r;
            c2v[mf * 4 + r]  = c2[row];
            cidv[mf * 4 + r] = cid[row];
            dnv[mf * 4 + r]  = (PASS == 2) ? dneg[row] : 0.f;   // dn^2
        }

    float rs[8], rc[8];
    #pragma unroll
    for (int i = 0; i < 8; ++i) { rs[i] = 0.f; rc[i] = 0.f; }
    float psum = 0.f, pcnt = 0.f;

    for (int step = 0; step < STEPS; ++step) {
        const int col0 = colw0 + step * 128;
        const unsigned short* bnext = (step == STEPS - 1)
            ? (Xb + (size_t)(colw0 + lr) * DD + lc * 8)          // safe wrap
            : (bbase + (size_t)128 * DD);

        // x2/targets for THIS step: latency covered by the kk loop below
        float x2v[4]; int tgv[4];
        #pragma unroll
        for (int nf = 0; nf < 4; ++nf) {
            int cc = col0 + nf * 16 + lr;
            x2v[nf] = x2[cc];
            tgv[nf] = targets[cc];
        }

        f32x4 acc[2][4];
        #pragma unroll
        for (int a = 0; a < 2; ++a)
            #pragma unroll
            for (int b = 0; b < 4; ++b) acc[a][b] = (f32x4){0.f, 0.f, 0.f, 0.f};

        #pragma unroll
        for (int kk = 0; kk < 8; ++kk) {
            const int s = kk & 3;
            short8 af0 = *(const short8*)&As[((kk * 4) + wr * 2 + 0) * 512 + l * 8];
            short8 af1 = *(const short8*)&As[((kk * 4) + wr * 2 + 1) * 512 + l * 8];
            __builtin_amdgcn_s_setprio(1);
            #pragma unroll
            for (int nf = 0; nf < 4; ++nf) {
                acc[0][nf] = __builtin_amdgcn_mfma_f32_16x16x32_bf16(af0, bR[s][nf], acc[0][nf], 0, 0, 0);
                acc[1][nf] = __builtin_amdgcn_mfma_f32_16x16x32_bf16(af1, bR[s][nf], acc[1][nf], 0, 0, 0);
            }
            __builtin_amdgcn_s_setprio(0);
            // reissue slot s for kk+4 (kk>=4 -> next step's kk-4, in flight
            // across the epilogue)
            {
                const unsigned short* nb = (kk < 4) ? bbase : bnext;
                const int kidx = (kk + 4) & 7;
                #pragma unroll
                for (int nf = 0; nf < 4; ++nf)
                    bR[s][nf] = *(const short8*)(nb + (size_t)(nf * 16) * DD + kidx * 32);
            }
        }

        // ---- fused epilogue -> persistent registers ----
        #pragma unroll
        for (int mf = 0; mf < 2; ++mf)
            #pragma unroll
            for (int nf = 0; nf < 4; ++nf)
                #pragma unroll
                for (int r = 0; r < 4; ++r) {
                    const int i = mf * 4 + r;
                    float d2 = fmaf(-2.f, acc[mf][nf][r], c2v[i] + x2v[nf]);
                    float d2c = fmaxf(d2, 1e-12f);
                    float dist = __builtin_amdgcn_sqrtf(d2c);
                    bool valid = d2 > 1e-12f;
                    bool isneg = (cidv[i] != tgv[nf]);
                    if (PASS == 1) {
                        float mn = (valid && isneg) ? 1.f : 0.f;
                        float mp = (valid && !isneg) ? 1.f : 0.f;
                        rs[i] = fmaf(mn, dist, rs[i]);  rc[i] += mn;
                        psum  = fmaf(mp, dist, psum);   pcnt  += mp;
                    } else {
                        float mh = (valid && isneg && d2c < dnv[i]) ? 1.f : 0.f;
                        rs[i] = fmaf(mh, dist, rs[i]);  rc[i] += mh;
                    }
                }

        bbase = bnext;
    }

    // ---- block-end reduction over the 16 lr-lanes ----
    #pragma unroll
    for (int i = 0; i < 8; ++i)
        #pragma unroll
        for (int m = 1; m < 16; m <<= 1) {
            rs[i] += __shfl_xor(rs[i], m, 64);
            rc[i] += __shfl_xor(rc[i], m, 64);
        }
    if (lr == 0) {
        float* S = (PASS == 1) ? negsum : hardsum;
        float* C = (PASS == 1) ? negcnt : hardcnt;
        #pragma unroll
        for (int mf = 0; mf < 2; ++mf)
            #pragma unroll
            for (int r = 0; r < 4; ++r) {
                int row = gr0 + mf * 16 + lc * 4 + r;
                atomicAdd(&S[row], rs[mf * 4 + r]);
                atomicAdd(&C[row], rc[mf * 4 + r]);
            }
    }

    if (PASS == 1) {
        #pragma unroll
        for (int m = 1; m < 64; m <<= 1) {
            psum += __shfl_xor(psum, m, 64);
            pcnt += __shfl_xor(pcnt, m, 64);
        }
        if (l == 0) { red[w] = psum; red[4 + w] = pcnt; }
        __syncthreads();
        if (tid == 0) {
            atomicAdd(&scal[0], red[0] + red[1] + red[2] + red[3]);
            atomicAdd(&scal[1], red[4] + red[5] + red[6] + red[7]);
        }
    }
}

__global__ void final_k(const float* __restrict__ hardsum,
                        const float* __restrict__ hardcnt,
                        const float* __restrict__ scal, float* out) {
    float s = 0.f;
    for (int c = threadIdx.x; c < IDN; c += 256)
        s += hardsum[c] / fmaxf(hardcnt[c], 1.0f);
    #pragma unroll
    for (int m = 1; m < 64; m <<= 1) s += __shfl_xor(s, m, 64);
    __shared__ float sb[4];
    int lane = threadIdx.x & 63, w = threadIdx.x >> 6;
    if (lane == 0) sb[w] = s;
    __syncthreads();
    if (threadIdx.x == 0) {
        float an = (sb[0] + sb[1] + sb[2] + sb[3]) / (float)IDN;
        float ap = scal[0] / scal[1];
        out[0] = ap / an;
    }
}

// ---------------- launch ----------------

extern "C" void kernel_launch(void* const* d_in, const int* in_sizes, int n_in,
                              void* d_out, int out_size, void* d_ws, size_t ws_size,
                              hipStream_t stream) {
    const float* inputs  = (const float*)d_in[0];
    const int*   targets = (const int*)d_in[1];
    float* out = (float*)d_out;

    char* p = (char*)d_ws;
    unsigned short* Xb = (unsigned short*)p;  p += (size_t)NS * DD * 2;
    unsigned short* Cb = (unsigned short*)p;  p += (size_t)IDN * DD * 2;
    float* x2   = (float*)p;  p += (size_t)NS * 4;
    float* c2   = (float*)p;  p += (size_t)IDN * 4;
    float* dneg = (float*)p;  p += (size_t)IDN * 4;
    int*   cid  = (int*)p;    p += (size_t)IDN * 4;
    int*   idx  = (int*)p;    p += (size_t)IDN * 16 * 4;
    char* zp = p;
    int*   icnt    = (int*)p;    p += (size_t)IDN * 4;
    float* negsum  = (float*)p;  p += (size_t)IDN * 4;
    float* negcnt  = (float*)p;  p += (size_t)IDN * 4;
    float* hardsum = (float*)p;  p += (size_t)IDN * 4;
    float* hardcnt = (float*)p;  p += (size_t)IDN * 4;
    float* scal    = (float*)p;  p += 64;

    hipMemsetAsync(zp, 0, (size_t)(p - zp), stream);
    build_idx_k<<<NS / 256, 256, 0, stream>>>(targets, icnt, idx);
    conv_k<<<NS / 4, 256, 0, stream>>>(inputs, Xb, x2);
    centers_k<<<IDN, 256, 0, stream>>>(inputs, idx, icnt, targets, Cb, c2, cid);

    mpass_k<1><<<1024, 256, 0, stream>>>(Cb, Xb, c2, x2, targets, cid,
                                         negsum, negcnt, dneg, hardsum, hardcnt, scal);
    dneg_k<<<IDN / 256, 256, 0, stream>>>(negsum, negcnt, dneg);
    mpass_k<2><<<1024, 256, 0, stream>>>(Cb, Xb, c2, x2, targets, cid,
                                         negsum, negcnt, dneg, hardsum, hardcnt, scal);
    final_k<<<1, 256, 0, stream>>>(hardsum, hardcnt, scal, out);
}

// Round 7
// 326.518 us; speedup vs baseline: 1.7628x; 1.7628x over previous
//
#include <hip/hip_runtime.h>
#include <hip/hip_bf16.h>

#define NS   32768
#define DD   256
#define NPOS 4
#define IDN  4096

typedef __attribute__((ext_vector_type(8))) short short8;
typedef __attribute__((ext_vector_type(4))) float f32x4;

__device__ __forceinline__ unsigned short f2bf(float f) {
    unsigned int u = __builtin_bit_cast(unsigned int, f);
    unsigned int r = (u + 0x7FFFu + ((u >> 16) & 1u)) >> 16;
    return (unsigned short)r;
}

__device__ __forceinline__ void gload16(const void* g, void* lds) {
    __builtin_amdgcn_global_load_lds(
        (const __attribute__((address_space(1))) unsigned int*)g,
        (__attribute__((address_space(3))) unsigned int*)lds, 16, 0, 0);
}

// ---------------- prep kernels ----------------

__global__ void build_idx_k(const int* __restrict__ targets, int* icnt, int* idx) {
    int i = blockIdx.x * 256 + threadIdx.x;
    if (i < NS) {
        int t = targets[i];
        int slot = atomicAdd(&icnt[t], 1);
        if (slot < 16) idx[t * 16 + slot] = i;
    }
}

__global__ void conv_k(const float* __restrict__ in, unsigned short* __restrict__ Xb,
                       float* __restrict__ x2) {
    int row  = blockIdx.x * 4 + (threadIdx.x >> 6);
    int lane = threadIdx.x & 63;
    const float4 v = *(const float4*)&in[(size_t)row * DD + lane * 4];
    ushort4 u;
    u.x = f2bf(v.x); u.y = f2bf(v.y); u.z = f2bf(v.z); u.w = f2bf(v.w);
    *(ushort4*)&Xb[(size_t)row * DD + lane * 4] = u;
    float sq = v.x * v.x + v.y * v.y + v.z * v.z + v.w * v.w;
    #pragma unroll
    for (int m = 1; m < 64; m <<= 1) sq += __shfl_xor(sq, m, 64);
    if (lane == 0) x2[row] = sq;
}

__global__ void centers_k(const float* __restrict__ in, const int* __restrict__ idx,
                          const int* __restrict__ icnt, const int* __restrict__ targets,
                          unsigned short* __restrict__ Cb, float* __restrict__ c2,
                          int* __restrict__ cid) {
    int c = blockIdx.x, d = threadIdx.x;
    int n = icnt[c]; if (n < 1) n = 1; if (n > 16) n = 16;
    float s = 0.f;
    for (int j = 0; j < n; ++j) s += in[(size_t)idx[c * 16 + j] * DD + d];
    float mean = s / (float)n;
    Cb[(size_t)c * DD + d] = f2bf(mean);
    float sq = mean * mean;
    #pragma unroll
    for (int m = 1; m < 64; m <<= 1) sq += __shfl_xor(sq, m, 64);
    __shared__ float sb[4];
    int lane = d & 63, w = d >> 6;
    if (lane == 0) sb[w] = sq;
    __syncthreads();
    if (d == 0) {
        c2[c] = sb[0] + sb[1] + sb[2] + sb[3];
        cid[c] = targets[c * NPOS];
    }
}

__global__ void dneg_k(const float* __restrict__ negsum,
                       const float* __restrict__ negcnt, float* dneg) {
    int c = blockIdx.x * 256 + threadIdx.x;
    if (c < IDN) {
        float d = negsum[c] / fmaxf(negcnt[c], 1.0f);
        dneg[c] = d * d;          // dn^2: pass-2 compares in d2 domain
    }
}

// ---------------- A-resident, B-through-LDS MFMA pass ----------------
// 256 blocks = 32 row-blocks x 8 chunks (1 block/CU); 512 threads (8 waves,
// 4 row x 2 col; wave tile 32x32). A panel 128x256 bf16 resident in LDS
// (64KB, staged once). B staged per 64-col slab into a 2x32KB LDS double
// buffer via global_load_lds -> B bytes hit VMEM ONCE PER BLOCK (r6 fix:
// per-wave duplicated B loads were the VMEM-issue ceiling). One barrier per
// step; its vmcnt-drain doubles as the "next slab landed" guarantee (loads
// get the whole ~1300cy step to fly -> structural latency hiding).

template <int PASS>
__global__ __launch_bounds__(512, 2)
void mpass_k(const unsigned short* __restrict__ Cb, const unsigned short* __restrict__ Xb,
             const float* __restrict__ c2, const float* __restrict__ x2,
             const int* __restrict__ targets, const int* __restrict__ cid,
             float* negsum, float* negcnt, const float* __restrict__ dneg,
             float* hardsum, float* hardcnt, float* scal) {
    __shared__ unsigned short As[64 * 512];      // [kk*8+rb][lane*8]  64KB
    __shared__ unsigned short Bs[2][32 * 512];   // [kk*4+cb][lane*8]  2x32KB
    __shared__ float red[16];

    const int tid = threadIdx.x;
    const int l  = tid & 63;
    const int w  = tid >> 6;      // wave 0..7
    const int wr = w >> 1;        // 0..3 : row quarter (32 rows)
    const int wc = w & 1;         // 0..1 : col half of slab (32 cols)
    const int lr = l & 15;
    const int lc = l >> 4;
    const int bid = blockIdx.x;
    const int ch = bid & 7;       // chunk == XCD
    const int bm = bid >> 3;      // row block 0..31
    const int colbase = ch * 4096;

    // ---- prologue staging: A full panel + B slab 0 ----
    {
        const unsigned short* asrc = Cb + (size_t)(bm * 128 + lr) * DD + w * 32 + lc * 8;
        #pragma unroll
        for (int rb = 0; rb < 8; ++rb)
            gload16(asrc + (size_t)rb * 16 * DD, &As[(w * 8 + rb) * 512]);
        const unsigned short* bsrc = Xb + (size_t)(colbase + lr) * DD + w * 32 + lc * 8;
        #pragma unroll
        for (int cb = 0; cb < 4; ++cb)
            gload16(bsrc + (size_t)cb * 16 * DD, &Bs[0][(w * 4 + cb) * 512]);
    }
    __syncthreads();

    // ---- per-row constants ----
    const int gr0 = bm * 128 + wr * 32;
    float c2v[8]; int cidv[8]; float dnv[8];
    #pragma unroll
    for (int mf = 0; mf < 2; ++mf)
        #pragma unroll
        for (int r = 0; r < 4; ++r) {
            int row = gr0 + mf * 16 + lc * 4 + r;
            c2v[mf * 4 + r]  = c2[row];
            cidv[mf * 4 + r] = cid[row];
            dnv[mf * 4 + r]  = (PASS == 2) ? dneg[row] : 0.f;   // dn^2
        }

    float rs[8], rc[8];
    #pragma unroll
    for (int i = 0; i < 8; ++i) { rs[i] = 0.f; rc[i] = 0.f; }
    float psum = 0.f, pcnt = 0.f;

    for (int step = 0; step < 64; ++step) {
        const int cur = step & 1;

        // stage NEXT slab into the other buffer (lands during this step)
        if (step < 63) {
            const unsigned short* bsrc =
                Xb + (size_t)(colbase + (step + 1) * 64 + lr) * DD + w * 32 + lc * 8;
            #pragma unroll
            for (int cb = 0; cb < 4; ++cb)
                gload16(bsrc + (size_t)cb * 16 * DD, &Bs[cur ^ 1][(w * 4 + cb) * 512]);
        }

        // this step's column metadata (consumed at epilogue -> latency hidden)
        float x2v[2]; int tgv[2];
        #pragma unroll
        for (int nf = 0; nf < 2; ++nf) {
            int cc = colbase + step * 64 + wc * 32 + nf * 16 + lr;
            x2v[nf] = x2[cc];
            tgv[nf] = targets[cc];
        }

        f32x4 acc[2][2];
        #pragma unroll
        for (int a = 0; a < 2; ++a)
            #pragma unroll
            for (int b = 0; b < 2; ++b) acc[a][b] = (f32x4){0.f, 0.f, 0.f, 0.f};

        #pragma unroll
        for (int kk = 0; kk < 8; ++kk) {
            short8 af0 = *(const short8*)&As[((kk * 8) + wr * 2 + 0) * 512 + l * 8];
            short8 af1 = *(const short8*)&As[((kk * 8) + wr * 2 + 1) * 512 + l * 8];
            short8 bf0 = *(const short8*)&Bs[cur][((kk * 4) + wc * 2 + 0) * 512 + l * 8];
            short8 bf1 = *(const short8*)&Bs[cur][((kk * 4) + wc * 2 + 1) * 512 + l * 8];
            acc[0][0] = __builtin_amdgcn_mfma_f32_16x16x32_bf16(af0, bf0, acc[0][0], 0, 0, 0);
            acc[0][1] = __builtin_amdgcn_mfma_f32_16x16x32_bf16(af0, bf1, acc[0][1], 0, 0, 0);
            acc[1][0] = __builtin_amdgcn_mfma_f32_16x16x32_bf16(af1, bf0, acc[1][0], 0, 0, 0);
            acc[1][1] = __builtin_amdgcn_mfma_f32_16x16x32_bf16(af1, bf1, acc[1][1], 0, 0, 0);
        }

        // ---- fused epilogue -> persistent registers ----
        #pragma unroll
        for (int mf = 0; mf < 2; ++mf)
            #pragma unroll
            for (int nf = 0; nf < 2; ++nf)
                #pragma unroll
                for (int r = 0; r < 4; ++r) {
                    const int i = mf * 4 + r;
                    float d2 = fmaf(-2.f, acc[mf][nf][r], c2v[i] + x2v[nf]);
                    float d2c = fmaxf(d2, 1e-12f);
                    float dist = __builtin_amdgcn_sqrtf(d2c);
                    bool valid = d2 > 1e-12f;
                    bool isneg = (cidv[i] != tgv[nf]);
                    if (PASS == 1) {
                        float mn = (valid && isneg) ? 1.f : 0.f;
                        float mp = (valid && !isneg) ? 1.f : 0.f;
                        rs[i] = fmaf(mn, dist, rs[i]);  rc[i] += mn;
                        psum  = fmaf(mp, dist, psum);   pcnt  += mp;
                    } else {
                        float mh = (valid && isneg && d2c < dnv[i]) ? 1.f : 0.f;
                        rs[i] = fmaf(mh, dist, rs[i]);  rc[i] += mh;
                    }
                }

        // one barrier per step: drains the staging loads (slab ready) and
        // fences buffer reuse for the next step
        __syncthreads();
    }

    // ---- block-end reduction over the 16 lr-lanes ----
    #pragma unroll
    for (int i = 0; i < 8; ++i)
        #pragma unroll
        for (int m = 1; m < 16; m <<= 1) {
            rs[i] += __shfl_xor(rs[i], m, 64);
            rc[i] += __shfl_xor(rc[i], m, 64);
        }
    if (lr == 0) {
        float* S = (PASS == 1) ? negsum : hardsum;
        float* C = (PASS == 1) ? negcnt : hardcnt;
        #pragma unroll
        for (int mf = 0; mf < 2; ++mf)
            #pragma unroll
            for (int r = 0; r < 4; ++r) {
                int row = gr0 + mf * 16 + lc * 4 + r;
                atomicAdd(&S[row], rs[mf * 4 + r]);
                atomicAdd(&C[row], rc[mf * 4 + r]);
            }
    }

    if (PASS == 1) {
        #pragma unroll
        for (int m = 1; m < 64; m <<= 1) {
            psum += __shfl_xor(psum, m, 64);
            pcnt += __shfl_xor(pcnt, m, 64);
        }
        if (l == 0) { red[w] = psum; red[8 + w] = pcnt; }
        __syncthreads();
        if (tid == 0) {
            float s0 = 0.f, s1 = 0.f;
            #pragma unroll
            for (int i = 0; i < 8; ++i) { s0 += red[i]; s1 += red[8 + i]; }
            atomicAdd(&scal[0], s0);
            atomicAdd(&scal[1], s1);
        }
    }
}

__global__ void final_k(const float* __restrict__ hardsum,
                        const float* __restrict__ hardcnt,
                        const float* __restrict__ scal, float* out) {
    float s = 0.f;
    for (int c = threadIdx.x; c < IDN; c += 256)
        s += hardsum[c] / fmaxf(hardcnt[c], 1.0f);
    #pragma unroll
    for (int m = 1; m < 64; m <<= 1) s += __shfl_xor(s, m, 64);
    __shared__ float sb[4];
    int lane = threadIdx.x & 63, w = threadIdx.x >> 6;
    if (lane == 0) sb[w] = s;
    __syncthreads();
    if (threadIdx.x == 0) {
        float an = (sb[0] + sb[1] + sb[2] + sb[3]) / (float)IDN;
        float ap = scal[0] / scal[1];
        out[0] = ap / an;
    }
}

// ---------------- launch ----------------

extern "C" void kernel_launch(void* const* d_in, const int* in_sizes, int n_in,
                              void* d_out, int out_size, void* d_ws, size_t ws_size,
                              hipStream_t stream) {
    const float* inputs  = (const float*)d_in[0];
    const int*   targets = (const int*)d_in[1];
    float* out = (float*)d_out;

    char* p = (char*)d_ws;
    unsigned short* Xb = (unsigned short*)p;  p += (size_t)NS * DD * 2;
    unsigned short* Cb = (unsigned short*)p;  p += (size_t)IDN * DD * 2;
    float* x2   = (float*)p;  p += (size_t)NS * 4;
    float* c2   = (float*)p;  p += (size_t)IDN * 4;
    float* dneg = (float*)p;  p += (size_t)IDN * 4;
    int*   cid  = (int*)p;    p += (size_t)IDN * 4;
    int*   idx  = (int*)p;    p += (size_t)IDN * 16 * 4;
    char* zp = p;
    int*   icnt    = (int*)p;    p += (size_t)IDN * 4;
    float* negsum  = (float*)p;  p += (size_t)IDN * 4;
    float* negcnt  = (float*)p;  p += (size_t)IDN * 4;
    float* hardsum = (float*)p;  p += (size_t)IDN * 4;
    float* hardcnt = (float*)p;  p += (size_t)IDN * 4;
    float* scal    = (float*)p;  p += 64;

    hipMemsetAsync(zp, 0, (size_t)(p - zp), stream);
    build_idx_k<<<NS / 256, 256, 0, stream>>>(targets, icnt, idx);
    conv_k<<<NS / 4, 256, 0, stream>>>(inputs, Xb, x2);
    centers_k<<<IDN, 256, 0, stream>>>(inputs, idx, icnt, targets, Cb, c2, cid);

    mpass_k<1><<<256, 512, 0, stream>>>(Cb, Xb, c2, x2, targets, cid,
                                        negsum, negcnt, dneg, hardsum, hardcnt, scal);
    dneg_k<<<IDN / 256, 256, 0, stream>>>(negsum, negcnt, dneg);
    mpass_k<2><<<256, 512, 0, stream>>>(Cb, Xb, c2, x2, targets, cid,
                                        negsum, negcnt, dneg, hardsum, hardcnt, scal);
    final_k<<<1, 256, 0, stream>>>(hardsum, hardcnt, scal, out);
}